// Round 8
// baseline (241.346 us; speedup 1.0000x reference)
//
#include <hip/hip_runtime.h>
#include <hip/hip_bf16.h>

typedef unsigned short u16;
typedef __bf16 bf16x8 __attribute__((ext_vector_type(8)));
typedef float f32x4 __attribute__((ext_vector_type(4)));
typedef unsigned short u16x8 __attribute__((ext_vector_type(8)));
typedef unsigned short u16x4 __attribute__((ext_vector_type(4)));

__device__ __forceinline__ float bf2f(u16 u) {
  unsigned x = ((unsigned)u) << 16;
  return __builtin_bit_cast(float, x);
}
__device__ __forceinline__ u16 f2bf(float f) {
  unsigned u = __builtin_bit_cast(unsigned, f);
  u += 0x7fffu + ((u >> 16) & 1u);
  return (u16)(u >> 16);
}

// async global -> LDS, 16B per lane; lds base is wave-uniform,
// HW scatters at base + lane*16.
__device__ __forceinline__ void gload16(const u16* g, u16* lds) {
  __builtin_amdgcn_global_load_lds(
      (const __attribute__((address_space(1))) void*)g,
      (__attribute__((address_space(3))) void*)lds,
      16, 0, 0);
}

// -------------------------------------------------------------------------
// C[M,N] = A[M,K] * B[N,K]^T, bf16 row-major, strides lda/ldb.
// 128x128 tile, BK in {64,128}, 4 waves x (64x64 per wave, 4x4 MFMA
// 16x16x32).  LDS: [128][BK] u16 rows; each row's 16B chunks XOR-swizzled
// (slot c ^ (row&7)) -> conflict-free banking while keeping the
// global_load_lds lane scatter contiguous (global address permuted).
// Fragment read address decomposed bit-exactly (j = s*4+q, m = row&7):
//   slot*8elems = (q^(m&3))*8 + ((s&1)^(m>>2))*32 + (s>>1)*64
// so the s-loop variation is a 64B toggle + 128B immediate -> compiler can
// emit ds_read_b128 with folded offsets (R7's 4-bit XOR form coincided
// with 4.2M bank-conflict cycles at BK=128; addresses here are identical,
// only the expression differs).
// Block map: by = (b&7) + 8*(b/(8*NX)) -> A-panel sharers on one XCD.
// K-loop: plain 2-barrier structure.  Established: split-K atomics regress
// (R2/R4), source-level vmcnt pipelining is compiler-defeated (R6, m131),
// BK=128 halves the fixed per-iter drain stall for the 1-block/CU PV (R7).
// OUT_MODE: 0 = f32 store, 1 = bf16 store (scaled by cscale).
// -------------------------------------------------------------------------
template <int OUT_MODE, int NX, int BK>
__device__ __forceinline__ void gemm_body(
    const u16* __restrict__ A, int lda,
    const u16* __restrict__ B, int ldb,
    void* __restrict__ C, int ldc, int K, float cscale)
{
  __shared__ __align__(16) u16 As[128 * BK];
  __shared__ __align__(16) u16 Bs[128 * BK];

  constexpr int CPR = BK / 8;    // 16B chunks per row: 8 (BK=64) / 16 (BK=128)
  constexpr int RPG = 512 / BK;  // rows per gload16: 8 / 4
  constexpr int IPW = 32 / RPG;  // gload16 per operand per wave: 4 / 8

  const int b = blockIdx.x;
  const int by = (b & 7) + 8 * (b / (8 * NX));
  const int bx = (b >> 3) % NX;
  const int m0 = by * 128, n0 = bx * 128;

  const int t = threadIdx.x;
  const int w = t >> 6, l = t & 63;
  const int srow = l / CPR;                  // staging row within group
  const int lc = l % CPR;                    // staging chunk slot within row
  const int wm = (w >> 1) * 64, wn = (w & 1) * 64;
  const int fr = l & 15;                     // fragment row
  const int q = l >> 4;                      // quarter-wave 0..3

  f32x4 acc[4][4] = {};

  for (int kt = 0; kt < K; kt += BK) {
    __syncthreads();
#pragma unroll
    for (int j = 0; j < IPW; ++j) {
      const int rr = RPG * (IPW * w + j);    // wave-uniform row-group base
      const int ga = rr + srow;              // tile row this lane feeds
      const int sch = ((lc ^ (ga & 7))) * 8; // swizzled global chunk (elems)
      gload16(A + (size_t)(m0 + ga) * lda + kt + sch, As + rr * BK);
      gload16(B + (size_t)(n0 + ga) * ldb + kt + sch, Bs + rr * BK);
    }
    __syncthreads();

#pragma unroll
    for (int s = 0; s < BK / 32; ++s) {      // K=32 MFMA steps per tile
      bf16x8 af[4], bfr[4];
#pragma unroll
      for (int i = 0; i < 4; ++i) {
        const int ra = wm + 16 * i + fr;
        const int ma = ra & 7;
        af[i] = *(const bf16x8*)(As + ra * BK + (q ^ (ma & 3)) * 8
                                 + (((s & 1) ^ (ma >> 2)) * 32) + (s >> 1) * 64);
      }
#pragma unroll
      for (int i = 0; i < 4; ++i) {
        const int rb = wn + 16 * i + fr;
        const int mb = rb & 7;
        bfr[i] = *(const bf16x8*)(Bs + rb * BK + (q ^ (mb & 3)) * 8
                                  + (((s & 1) ^ (mb >> 2)) * 32) + (s >> 1) * 64);
      }
#pragma unroll
      for (int i = 0; i < 4; ++i)
#pragma unroll
        for (int jj = 0; jj < 4; ++jj)
          acc[i][jj] = __builtin_amdgcn_mfma_f32_16x16x32_bf16(af[i], bfr[jj], acc[i][jj], 0, 0, 0);
    }
  }

  // C/D layout (m89-verified): col = lane&15, row = (lane>>4)*4 + reg
  const int er = q * 4;
  const int ec = l & 15;
#pragma unroll
  for (int i = 0; i < 4; ++i)
#pragma unroll
    for (int jj = 0; jj < 4; ++jj)
#pragma unroll
      for (int r = 0; r < 4; ++r) {
        const size_t idx = (size_t)(m0 + wm + 16 * i + er + r) * ldc + (n0 + wn + 16 * jj + ec);
        if (OUT_MODE == 1) ((u16*)C)[idx] = f2bf(acc[i][jj][r] * cscale);
        else               ((float*)C)[idx] = acc[i][jj][r];
      }
}

// distinct names per stage so rocprof separates them
__global__ __launch_bounds__(256) void gemm_qkv(const u16* __restrict__ A,
                                                const u16* __restrict__ B,
                                                u16* __restrict__ C) {
  gemm_body<1, 24, 64>(A, 1024, B, 1024, C, 3072, 1024, 1.0f);
}
__global__ __launch_bounds__(256) void gemm_score(const u16* __restrict__ QKV,
                                                  u16* __restrict__ S) {
  // scale 1/sqrt(1024) folded into the epilogue store
  gemm_body<1, 32, 64>(QKV, 3072, QKV + 1024, 3072, S, 4096, 1024, 0.03125f);
}
__global__ __launch_bounds__(256) void gemm_pv(const u16* __restrict__ S,
                                               const u16* __restrict__ Vt,
                                               float* __restrict__ O) {
  // 1 block/CU -> BK=128 (64 KB LDS) halves the per-iter stall count
  gemm_body<0, 8, 128>(S, 4096, Vt, 4096, O, 1024, 4096, 1.0f);
}

// -------------------------------------------------------------------------
// prep: E f32->bf16 cast (blocks 0..4095) + all three W transposes
// (blocks 4096..7167; 1024 32x32 tiles per matrix), one dispatch.
// -------------------------------------------------------------------------
__global__ __launch_bounds__(256) void prep(
    const float* __restrict__ E,
    const float* __restrict__ w0, const float* __restrict__ w1,
    const float* __restrict__ w2,
    u16* __restrict__ Ebf, u16* __restrict__ Wt)
{
  int b = blockIdx.x;
  if (b < 4096) {
    const int i = (b * 256 + threadIdx.x) * 4;
    float4 f = *(const float4*)(E + i);
    u16x4 o;
    o.x = f2bf(f.x); o.y = f2bf(f.y); o.z = f2bf(f.z); o.w = f2bf(f.w);
    *(u16x4*)(Ebf + i) = o;
  } else {
    b -= 4096;
    const int which = b >> 10;           // 0..2
    const int tile = b & 1023;
    const float* in = (which == 0) ? w0 : (which == 1) ? w1 : w2;
    u16* o = Wt + (size_t)which * 1024 * 1024;
    const int c0 = (tile & 31) * 32, r0 = (tile >> 5) * 32;
    __shared__ u16 tl[32][33];
    const int tx = threadIdx.x & 31, ty0 = threadIdx.x >> 5;  // ty0: 0..7
#pragma unroll
    for (int k = 0; k < 4; ++k) {
      const int ty = ty0 + k * 8;
      tl[ty][tx] = f2bf(in[(size_t)(r0 + ty) * 1024 + c0 + tx]);
    }
    __syncthreads();
#pragma unroll
    for (int k = 0; k < 4; ++k) {
      const int ty = ty0 + k * 8;
      o[(size_t)(c0 + ty) * 1024 + r0 + tx] = tl[tx][ty];
    }
  }
}

// -------------------------------------------------------------------------
// bf16 transpose (for V -> V^T): out[c*ldout + r] = in[r*ldin + c]
// -------------------------------------------------------------------------
__global__ __launch_bounds__(1024) void transpose_bf16(
    const u16* __restrict__ in, int ldin, u16* __restrict__ out, int ldout)
{
  __shared__ u16 tile[32][33];
  const int c0 = blockIdx.x * 32, r0 = blockIdx.y * 32;
  const int tx = threadIdx.x, ty = threadIdx.y;
  tile[ty][tx] = in[(size_t)(r0 + ty) * ldin + c0 + tx];
  __syncthreads();
  out[(size_t)(c0 + ty) * ldout + r0 + tx] = tile[tx][ty];
}

// -------------------------------------------------------------------------
// row softmax, in-place on bf16 S[4096][4096] (scale already applied).
// -------------------------------------------------------------------------
__global__ __launch_bounds__(256) void softmax_rows(u16* __restrict__ S) {
  const int N = 4096;
  u16* p = S + (size_t)blockIdx.x * N;
  const int t = threadIdx.x;
  u16x8 u0 = ((const u16x8*)p)[t * 2];
  u16x8 u1 = ((const u16x8*)p)[t * 2 + 1];
  float v[16];
#pragma unroll
  for (int i = 0; i < 8; ++i) v[i] = bf2f(u0[i]);
#pragma unroll
  for (int i = 0; i < 8; ++i) v[8 + i] = bf2f(u1[i]);

  float m = -1e30f;
#pragma unroll
  for (int i = 0; i < 16; ++i) m = fmaxf(m, v[i]);
#pragma unroll
  for (int off = 32; off; off >>= 1) m = fmaxf(m, __shfl_xor(m, off));
  __shared__ float red[8];
  if ((t & 63) == 0) red[t >> 6] = m;
  __syncthreads();
  m = fmaxf(fmaxf(red[0], red[1]), fmaxf(red[2], red[3]));

  float s = 0.f;
#pragma unroll
  for (int i = 0; i < 16; ++i) { v[i] = __expf(v[i] - m); s += v[i]; }
#pragma unroll
  for (int off = 32; off; off >>= 1) s += __shfl_xor(s, off);
  if ((t & 63) == 0) red[4 + (t >> 6)] = s;
  __syncthreads();
  s = (red[4] + red[5]) + (red[6] + red[7]);
  const float inv = 1.0f / s;

  u16x8 o0, o1;
#pragma unroll
  for (int i = 0; i < 8; ++i) o0[i] = f2bf(v[i] * inv);
#pragma unroll
  for (int i = 0; i < 8; ++i) o1[i] = f2bf(v[8 + i] * inv);
  ((u16x8*)p)[t * 2] = o0;
  ((u16x8*)p)[t * 2 + 1] = o1;
}

// -------------------------------------------------------------------------
// S=4096, D_IN=1024, D_OUT=1024.  fp32 in, fp32 out.
// ws layout (bytes): Ebf 8MB | Wt 6MB | QKV 24MB | Vt 8MB | S 32MB = 78MB
// -------------------------------------------------------------------------
extern "C" void kernel_launch(void* const* d_in, const int* in_sizes, int n_in,
                              void* d_out, int out_size, void* d_ws, size_t ws_size,
                              hipStream_t stream) {
  const float* E  = (const float*)d_in[0];
  const float* Wq = (const float*)d_in[1];
  const float* Wk = (const float*)d_in[2];
  const float* Wv = (const float*)d_in[3];
  float* Out = (float*)d_out;

  char* w = (char*)d_ws;
  u16* Ebf = (u16*)(w);
  u16* Wt  = (u16*)(w + (size_t)(8u << 20));
  u16* QKV = (u16*)(w + (size_t)(14u << 20));
  u16* Vt  = (u16*)(w + (size_t)(38u << 20));
  u16* S   = (u16*)(w + (size_t)(46u << 20));

  // stage 0: cast E + transpose W's, one dispatch
  prep<<<7168, 256, 0, stream>>>(E, Wq, Wk, Wv, Ebf, Wt);

  // stage 1: QKV = E @ Wt^T   [4096 x 3072], K=1024
  gemm_qkv<<<768, 256, 0, stream>>>(Ebf, Wt, QKV);

  // V^T for the PV GEMM
  transpose_bf16<<<dim3(32, 128), dim3(32, 32), 0, stream>>>(QKV + 2048, 3072, Vt, 4096);

  // stage 2: S = (Q @ K^T) / 32   [4096 x 4096], K=1024
  gemm_score<<<1024, 256, 0, stream>>>(QKV, S);

  // stage 3: P = softmax(S) in place
  softmax_rows<<<4096, 256, 0, stream>>>(S);

  // stage 4: Out = P @ Vt^T  [4096 x 1024], K=4096, BK=128
  gemm_pv<<<256, 256, 0, stream>>>(S, Vt, Out);
}

// Round 9
// 223.254 us; speedup vs baseline: 1.0810x; 1.0810x over previous
//
#include <hip/hip_runtime.h>
#include <hip/hip_bf16.h>

typedef unsigned short u16;
typedef __bf16 bf16x8 __attribute__((ext_vector_type(8)));
typedef float f32x4 __attribute__((ext_vector_type(4)));
typedef unsigned short u16x8 __attribute__((ext_vector_type(8)));
typedef unsigned short u16x4 __attribute__((ext_vector_type(4)));

__device__ __forceinline__ float bf2f(u16 u) {
  unsigned x = ((unsigned)u) << 16;
  return __builtin_bit_cast(float, x);
}
__device__ __forceinline__ u16 f2bf(float f) {
  unsigned u = __builtin_bit_cast(unsigned, f);
  u += 0x7fffu + ((u >> 16) & 1u);
  return (u16)(u >> 16);
}

// async global -> LDS, 16B per lane; lds base is wave-uniform,
// HW scatters at base + lane*16.
__device__ __forceinline__ void gload16(const u16* g, u16* lds) {
  __builtin_amdgcn_global_load_lds(
      (const __attribute__((address_space(1))) void*)g,
      (__attribute__((address_space(3))) void*)lds,
      16, 0, 0);
}

// -------------------------------------------------------------------------
// C[M,N] = A[M,K(range)] * B[N,K]^T, bf16 row-major, strides lda/ldb.
// 128x128 tile, BK in {64,128}, 4 waves x (64x64 per wave, 4x4 MFMA
// 16x16x32).  LDS: [128][BK] u16 rows; 16B chunks XOR-swizzled
// (slot c ^ (row&7)) -> conflict-free banking with a contiguous
// global_load_lds lane scatter (global address permuted per lane).
// Block map: by = (b&7) + 8*(b/(8*NX)) -> A-panel sharers on one XCD.
// K-loop: plain 2-barrier structure.  Session facts: atomic split-K
// regresses (R2/R4: write-through + coherence tax); source-level vmcnt
// pipelining is compiler-defeated (R6 = m131); BK=128 halves the fixed
// per-iter drain stall at low occupancy (R7: PV 85->65);
// SQ_LDS_BANK_CONFLICT==2^22 is a saturated counter artifact (R8).
// kt0/Kc select a K range (atomic-free split-K writes separate buffers).
// OUT_MODE: 0 = f32 store, 1 = bf16 store (scaled by cscale).
// -------------------------------------------------------------------------
template <int OUT_MODE, int NX, int BK>
__device__ __forceinline__ void gemm_body(
    const u16* __restrict__ A, int lda,
    const u16* __restrict__ B, int ldb,
    void* __restrict__ C, int ldc, int kt0, int Kc, float cscale)
{
  __shared__ __align__(16) u16 As[128 * BK];
  __shared__ __align__(16) u16 Bs[128 * BK];

  constexpr int CPR = BK / 8;    // 16B chunks per row: 8 (BK=64) / 16 (BK=128)
  constexpr int RPG = 512 / BK;  // rows per gload16: 8 / 4
  constexpr int IPW = 32 / RPG;  // gload16 per operand per wave: 4 / 8

  const int b = blockIdx.x;
  const int by = (b & 7) + 8 * (b / (8 * NX));
  const int bx = (b >> 3) % NX;
  const int m0 = by * 128, n0 = bx * 128;

  const int t = threadIdx.x;
  const int w = t >> 6, l = t & 63;
  const int srow = l / CPR;                  // staging row within group
  const int lc = l % CPR;                    // staging chunk slot within row
  const int wm = (w >> 1) * 64, wn = (w & 1) * 64;
  const int fr = l & 15;                     // fragment row
  const int q = l >> 4;                      // quarter-wave 0..3

  f32x4 acc[4][4] = {};

  for (int kk = 0; kk < Kc; kk += BK) {
    const int kt = kt0 + kk;
    __syncthreads();
#pragma unroll
    for (int j = 0; j < IPW; ++j) {
      const int rr = RPG * (IPW * w + j);    // wave-uniform row-group base
      const int ga = rr + srow;              // tile row this lane feeds
      const int sch = ((lc ^ (ga & 7))) * 8; // swizzled global chunk (elems)
      gload16(A + (size_t)(m0 + ga) * lda + kt + sch, As + rr * BK);
      gload16(B + (size_t)(n0 + ga) * ldb + kt + sch, Bs + rr * BK);
    }
    __syncthreads();

#pragma unroll
    for (int s = 0; s < BK / 32; ++s) {      // K=32 MFMA steps per tile
      const int j = s * 4 + q;               // global 16B chunk index
      bf16x8 af[4], bfr[4];
#pragma unroll
      for (int i = 0; i < 4; ++i) {
        const int ra = wm + 16 * i + fr;
        af[i] = *(const bf16x8*)(As + ra * BK + (j ^ (ra & 7)) * 8);
      }
#pragma unroll
      for (int i = 0; i < 4; ++i) {
        const int rb = wn + 16 * i + fr;
        bfr[i] = *(const bf16x8*)(Bs + rb * BK + (j ^ (rb & 7)) * 8);
      }
#pragma unroll
      for (int i = 0; i < 4; ++i)
#pragma unroll
        for (int jj = 0; jj < 4; ++jj)
          acc[i][jj] = __builtin_amdgcn_mfma_f32_16x16x32_bf16(af[i], bfr[jj], acc[i][jj], 0, 0, 0);
    }
  }

  // C/D layout (m89-verified): col = lane&15, row = (lane>>4)*4 + reg
  const int er = q * 4;
  const int ec = l & 15;
#pragma unroll
  for (int i = 0; i < 4; ++i)
#pragma unroll
    for (int jj = 0; jj < 4; ++jj)
#pragma unroll
      for (int r = 0; r < 4; ++r) {
        const size_t idx = (size_t)(m0 + wm + 16 * i + er + r) * ldc + (n0 + wn + 16 * jj + ec);
        if (OUT_MODE == 1) ((u16*)C)[idx] = f2bf(acc[i][jj][r] * cscale);
        else               ((float*)C)[idx] = acc[i][jj][r];
      }
}

// distinct names per stage so rocprof separates them
__global__ __launch_bounds__(256) void gemm_qkv(const u16* __restrict__ A,
                                                const u16* __restrict__ B,
                                                u16* __restrict__ C) {
  gemm_body<1, 24, 64>(A, 1024, B, 1024, C, 3072, 0, 1024, 1.0f);
}
__global__ __launch_bounds__(256) void gemm_score(const u16* __restrict__ QKV,
                                                  u16* __restrict__ S) {
  // scale 1/sqrt(1024) folded into the epilogue store
  gemm_body<1, 32, 64>(QKV, 3072, QKV + 1024, 3072, S, 4096, 0, 1024, 0.03125f);
}
__global__ __launch_bounds__(256) void gemm_pv(const u16* __restrict__ S,
                                               const u16* __restrict__ Vt,
                                               float* __restrict__ O0,
                                               float* __restrict__ O1) {
  // atomic-free split-K=2: z=0 -> d_out, z=1 -> fp32 partial in dead ws.
  // 512 blocks @ 64KB LDS = 2 co-resident blocks/CU -> cross-block overlap.
  float* C = blockIdx.z ? O1 : O0;
  gemm_body<0, 8, 128>(S, 4096, Vt, 4096, C, 1024, blockIdx.z * 2048, 2048, 1.0f);
}

// -------------------------------------------------------------------------
// Out += partial  (4M fp32, float4 per thread)
// -------------------------------------------------------------------------
__global__ __launch_bounds__(256) void reduce_add(float4* __restrict__ out,
                                                  const float4* __restrict__ p) {
  const int i = blockIdx.x * 256 + threadIdx.x;
  float4 a = out[i], b = p[i];
  out[i] = float4{a.x + b.x, a.y + b.y, a.z + b.z, a.w + b.w};
}

// -------------------------------------------------------------------------
// elementwise f32 -> bf16 cast, 4 elems/thread
// -------------------------------------------------------------------------
__global__ __launch_bounds__(256) void cast_f32_bf16(const float* __restrict__ in,
                                                     u16* __restrict__ out) {
  const int i = (blockIdx.x * 256 + threadIdx.x) * 4;
  float4 f = *(const float4*)(in + i);
  u16x4 o;
  o.x = f2bf(f.x); o.y = f2bf(f.y); o.z = f2bf(f.z); o.w = f2bf(f.w);
  *(u16x4*)(out + i) = o;
}

// -------------------------------------------------------------------------
// all three W [1024x1024] f32 -> bf16 transposes in one dispatch (z = which)
// -------------------------------------------------------------------------
__global__ __launch_bounds__(1024) void transpose_w3(
    const float* __restrict__ w0, const float* __restrict__ w1,
    const float* __restrict__ w2, u16* __restrict__ out)
{
  __shared__ u16 tile[32][33];
  const float* in = (blockIdx.z == 0) ? w0 : (blockIdx.z == 1) ? w1 : w2;
  u16* o = out + (size_t)blockIdx.z * 1024 * 1024;
  const int c0 = blockIdx.x * 32, r0 = blockIdx.y * 32;
  const int tx = threadIdx.x, ty = threadIdx.y;
  tile[ty][tx] = f2bf(in[(size_t)(r0 + ty) * 1024 + c0 + tx]);
  __syncthreads();
  o[(size_t)(c0 + ty) * 1024 + r0 + tx] = tile[tx][ty];
}

// -------------------------------------------------------------------------
// bf16 transpose (for V -> V^T): out[c*ldout + r] = in[r*ldin + c]
// -------------------------------------------------------------------------
__global__ __launch_bounds__(1024) void transpose_bf16(
    const u16* __restrict__ in, int ldin, u16* __restrict__ out, int ldout)
{
  __shared__ u16 tile[32][33];
  const int c0 = blockIdx.x * 32, r0 = blockIdx.y * 32;
  const int tx = threadIdx.x, ty = threadIdx.y;
  tile[ty][tx] = in[(size_t)(r0 + ty) * ldin + c0 + tx];
  __syncthreads();
  out[(size_t)(c0 + ty) * ldout + r0 + tx] = tile[tx][ty];
}

// -------------------------------------------------------------------------
// row softmax, in-place on bf16 S[4096][4096] (scale already applied).
// -------------------------------------------------------------------------
__global__ __launch_bounds__(256) void softmax_rows(u16* __restrict__ S) {
  const int N = 4096;
  u16* p = S + (size_t)blockIdx.x * N;
  const int t = threadIdx.x;
  u16x8 u0 = ((const u16x8*)p)[t * 2];
  u16x8 u1 = ((const u16x8*)p)[t * 2 + 1];
  float v[16];
#pragma unroll
  for (int i = 0; i < 8; ++i) v[i] = bf2f(u0[i]);
#pragma unroll
  for (int i = 0; i < 8; ++i) v[8 + i] = bf2f(u1[i]);

  float m = -1e30f;
#pragma unroll
  for (int i = 0; i < 16; ++i) m = fmaxf(m, v[i]);
#pragma unroll
  for (int off = 32; off; off >>= 1) m = fmaxf(m, __shfl_xor(m, off));
  __shared__ float red[8];
  if ((t & 63) == 0) red[t >> 6] = m;
  __syncthreads();
  m = fmaxf(fmaxf(red[0], red[1]), fmaxf(red[2], red[3]));

  float s = 0.f;
#pragma unroll
  for (int i = 0; i < 16; ++i) { v[i] = __expf(v[i] - m); s += v[i]; }
#pragma unroll
  for (int off = 32; off; off >>= 1) s += __shfl_xor(s, off);
  if ((t & 63) == 0) red[4 + (t >> 6)] = s;
  __syncthreads();
  s = (red[4] + red[5]) + (red[6] + red[7]);
  const float inv = 1.0f / s;

  u16x8 o0, o1;
#pragma unroll
  for (int i = 0; i < 8; ++i) o0[i] = f2bf(v[i] * inv);
#pragma unroll
  for (int i = 0; i < 8; ++i) o1[i] = f2bf(v[8 + i] * inv);
  ((u16x8*)p)[t * 2] = o0;
  ((u16x8*)p)[t * 2 + 1] = o1;
}

// -------------------------------------------------------------------------
// S=4096, D_IN=1024, D_OUT=1024.  fp32 in, fp32 out.
// ws layout (bytes): Ebf 8MB | Wt 6MB | QKV 24MB | Vt 8MB | S 32MB = 78MB
// PV partial (16MB fp32) reuses [0,16MB) -- Ebf/Wt/QKV-head are dead once
// score has completed (score consumes Q,K; PV consumes only S and Vt).
// -------------------------------------------------------------------------
extern "C" void kernel_launch(void* const* d_in, const int* in_sizes, int n_in,
                              void* d_out, int out_size, void* d_ws, size_t ws_size,
                              hipStream_t stream) {
  const float* E  = (const float*)d_in[0];
  const float* Wq = (const float*)d_in[1];
  const float* Wk = (const float*)d_in[2];
  const float* Wv = (const float*)d_in[3];
  float* Out = (float*)d_out;

  char* w = (char*)d_ws;
  u16* Ebf = (u16*)(w);
  u16* Wt  = (u16*)(w + (size_t)(8u << 20));
  u16* QKV = (u16*)(w + (size_t)(14u << 20));
  u16* Vt  = (u16*)(w + (size_t)(38u << 20));
  u16* S   = (u16*)(w + (size_t)(46u << 20));
  float* P1 = (float*)(w);                 // PV split-K partial, dead region

  // stage 0: casts / weight transposes (separate dispatches -- R8's merge
  // regressed; R7 structure restored)
  cast_f32_bf16<<<4096, 256, 0, stream>>>(E, Ebf);
  transpose_w3<<<dim3(32, 32, 3), dim3(32, 32), 0, stream>>>(Wq, Wk, Wv, Wt);

  // stage 1: QKV = E @ Wt^T   [4096 x 3072], K=1024
  gemm_qkv<<<768, 256, 0, stream>>>(Ebf, Wt, QKV);

  // V^T for the PV GEMM
  transpose_bf16<<<dim3(32, 128), dim3(32, 32), 0, stream>>>(QKV + 2048, 3072, Vt, 4096);

  // stage 2: S = (Q @ K^T) / 32   [4096 x 4096], K=1024
  gemm_score<<<1024, 256, 0, stream>>>(QKV, S);

  // stage 3: P = softmax(S) in place
  softmax_rows<<<4096, 256, 0, stream>>>(S);

  // stage 4: Out = P @ Vt^T  [4096 x 1024], K=4096, BK=128,
  //          atomic-free split-K=2 (z=0 -> Out, z=1 -> P1), then reduce
  gemm_pv<<<dim3(256, 1, 2), 256, 0, stream>>>(S, Vt, Out, P1);
  reduce_add<<<4096, 256, 0, stream>>>((float4*)Out, (const float4*)P1);
}

// Round 10
// 220.033 us; speedup vs baseline: 1.0969x; 1.0146x over previous
//
#include <hip/hip_runtime.h>
#include <hip/hip_bf16.h>

typedef unsigned short u16;
typedef __bf16 bf16x8 __attribute__((ext_vector_type(8)));
typedef float f32x4 __attribute__((ext_vector_type(4)));
typedef unsigned short u16x8 __attribute__((ext_vector_type(8)));
typedef unsigned short u16x4 __attribute__((ext_vector_type(4)));

__device__ __forceinline__ float bf2f(u16 u) {
  unsigned x = ((unsigned)u) << 16;
  return __builtin_bit_cast(float, x);
}
__device__ __forceinline__ u16 f2bf(float f) {
  unsigned u = __builtin_bit_cast(unsigned, f);
  u += 0x7fffu + ((u >> 16) & 1u);
  return (u16)(u >> 16);
}

// async global -> LDS, 16B per lane; lds base is wave-uniform,
// HW scatters at base + lane*16.
__device__ __forceinline__ void gload16(const u16* g, u16* lds) {
  __builtin_amdgcn_global_load_lds(
      (const __attribute__((address_space(1))) void*)g,
      (__attribute__((address_space(3))) void*)lds,
      16, 0, 0);
}

// -------------------------------------------------------------------------
// C[M,N] = A[M,K(range)] * B[N,K]^T, bf16 row-major, strides lda/ldb.
// 128x128 tile, BK in {64,128}, 4 waves x (64x64 per wave, 4x4 MFMA
// 16x16x32).  LDS (caller-provided): [128][BK] u16 rows; 16B chunks
// XOR-swizzled (slot c ^ (row&7)) -> conflict-free banking with a
// contiguous global_load_lds lane scatter (global address permuted).
// Block map: by = (bid&7) + 8*(bid/(8*NX)) -> A-panel sharers on one XCD.
// K-loop: plain 2-barrier structure.  Session facts: atomic split-K
// regresses (R2/R4); atomic-FREE split-K into separate buffers wins (R9);
// source-level vmcnt pipelining is compiler-defeated (R6 = m131); BK=128
// halves the fixed per-iter drain stall at low occupancy (R7: PV 85->65);
// SQ_LDS_BANK_CONFLICT==2^22 is a saturated counter artifact (R8).
// OUT_MODE: 0 = f32 store, 1 = bf16 store (scaled by cscale).
// -------------------------------------------------------------------------
template <int OUT_MODE, int NX, int BK>
__device__ __forceinline__ void gemm_body(
    const u16* __restrict__ A, int lda,
    const u16* __restrict__ B, int ldb,
    void* __restrict__ C, int ldc, int kt0, int Kc, float cscale,
    u16* As, u16* Bs, int bid)
{
  constexpr int CPR = BK / 8;    // 16B chunks per row: 8 (BK=64) / 16 (BK=128)
  constexpr int RPG = 512 / BK;  // rows per gload16: 8 / 4
  constexpr int IPW = 32 / RPG;  // gload16 per operand per wave: 4 / 8

  const int by = (bid & 7) + 8 * (bid / (8 * NX));
  const int bx = (bid >> 3) % NX;
  const int m0 = by * 128, n0 = bx * 128;

  const int t = threadIdx.x;
  const int w = t >> 6, l = t & 63;
  const int srow = l / CPR;                  // staging row within group
  const int lc = l % CPR;                    // staging chunk slot within row
  const int wm = (w >> 1) * 64, wn = (w & 1) * 64;
  const int fr = l & 15;                     // fragment row
  const int q = l >> 4;                      // quarter-wave 0..3

  f32x4 acc[4][4] = {};

  for (int kk = 0; kk < Kc; kk += BK) {
    const int kt = kt0 + kk;
    __syncthreads();
#pragma unroll
    for (int j = 0; j < IPW; ++j) {
      const int rr = RPG * (IPW * w + j);    // wave-uniform row-group base
      const int ga = rr + srow;              // tile row this lane feeds
      const int sch = ((lc ^ (ga & 7))) * 8; // swizzled global chunk (elems)
      gload16(A + (size_t)(m0 + ga) * lda + kt + sch, As + rr * BK);
      gload16(B + (size_t)(n0 + ga) * ldb + kt + sch, Bs + rr * BK);
    }
    __syncthreads();

#pragma unroll
    for (int s = 0; s < BK / 32; ++s) {      // K=32 MFMA steps per tile
      const int j = s * 4 + q;               // global 16B chunk index
      bf16x8 af[4], bfr[4];
#pragma unroll
      for (int i = 0; i < 4; ++i) {
        const int ra = wm + 16 * i + fr;
        af[i] = *(const bf16x8*)(As + ra * BK + (j ^ (ra & 7)) * 8);
      }
#pragma unroll
      for (int i = 0; i < 4; ++i) {
        const int rb = wn + 16 * i + fr;
        bfr[i] = *(const bf16x8*)(Bs + rb * BK + (j ^ (rb & 7)) * 8);
      }
#pragma unroll
      for (int i = 0; i < 4; ++i)
#pragma unroll
        for (int jj = 0; jj < 4; ++jj)
          acc[i][jj] = __builtin_amdgcn_mfma_f32_16x16x32_bf16(af[i], bfr[jj], acc[i][jj], 0, 0, 0);
    }
  }

  // C/D layout (m89-verified): col = lane&15, row = (lane>>4)*4 + reg
  const int er = q * 4;
  const int ec = l & 15;
#pragma unroll
  for (int i = 0; i < 4; ++i)
#pragma unroll
    for (int jj = 0; jj < 4; ++jj)
#pragma unroll
      for (int r = 0; r < 4; ++r) {
        const size_t idx = (size_t)(m0 + wm + 16 * i + er + r) * ldc + (n0 + wn + 16 * jj + ec);
        if (OUT_MODE == 1) ((u16*)C)[idx] = f2bf(acc[i][jj][r] * cscale);
        else               ((float*)C)[idx] = acc[i][jj][r];
      }
}

// -------------------------------------------------------------------------
// stage 1: QKV = E @ Wt^T   [4096 x 3072], K=1024
// -------------------------------------------------------------------------
__global__ __launch_bounds__(256) void gemm_qkv(const u16* __restrict__ A,
                                                const u16* __restrict__ B,
                                                u16* __restrict__ C) {
  __shared__ __align__(16) u16 As[128 * 64], Bs[128 * 64];
  gemm_body<1, 24, 64>(A, 1024, B, 1024, C, 3072, 0, 1024, 1.0f, As, Bs, blockIdx.x);
}

// -------------------------------------------------------------------------
// stage 2 merged: blocks 0..1023 = score GEMM S = (Q@K^T)/32;
// blocks 1024..5119 = V transpose (32x32 tiles, 4096 of them).  Both
// depend only on qkv output -> one dispatch saves a boundary.  The tV
// tile buffer ALIASES As so score keeps 32 KB LDS (5 blocks/CU).
// -------------------------------------------------------------------------
__global__ __launch_bounds__(256) void score_tv(const u16* __restrict__ QKV,
                                                u16* __restrict__ S,
                                                u16* __restrict__ Vt) {
  __shared__ __align__(16) u16 As[128 * 64], Bs[128 * 64];
  const int b = blockIdx.x;
  if (b < 1024) {
    gemm_body<1, 32, 64>(QKV, 3072, QKV + 1024, 3072, S, 4096, 0, 1024,
                         0.03125f, As, Bs, b);
  } else {
    const int v = b - 1024;                       // 0..4095
    const int c0 = (v & 31) * 32;                 // V col 0..1023
    const int r0 = (v >> 5) * 32;                 // V row 0..4095
    u16 (*tl)[33] = (u16(*)[33])As;               // 2.1 KB alias of As
    const int tx = threadIdx.x & 31, ty0 = threadIdx.x >> 5;
    const u16* Vin = QKV + 2048;                  // V cols of QKV (ld 3072)
#pragma unroll
    for (int k = 0; k < 4; ++k) {
      const int ty = ty0 + k * 8;
      tl[ty][tx] = Vin[(size_t)(r0 + ty) * 3072 + c0 + tx];
    }
    __syncthreads();
#pragma unroll
    for (int k = 0; k < 4; ++k) {
      const int ty = ty0 + k * 8;
      Vt[(size_t)(c0 + ty) * 4096 + r0 + tx] = tl[tx][ty];
    }
  }
}

// -------------------------------------------------------------------------
// stage 4: Out = P @ Vt^T, K=4096, BK=128, atomic-free split-K=2 (R9 win):
// z=0 -> d_out, z=1 -> fp32 partial in dead ws; reduce_add folds them.
// -------------------------------------------------------------------------
__global__ __launch_bounds__(256) void gemm_pv(const u16* __restrict__ S,
                                               const u16* __restrict__ Vt,
                                               float* __restrict__ O0,
                                               float* __restrict__ O1) {
  __shared__ __align__(16) u16 As[128 * 128], Bs[128 * 128];
  float* C = blockIdx.z ? O1 : O0;
  gemm_body<0, 8, 128>(S, 4096, Vt, 4096, C, 1024, blockIdx.z * 2048, 2048,
                       1.0f, As, Bs, blockIdx.x);
}

// -------------------------------------------------------------------------
// Out += partial  (4M fp32, float4 per thread)
// -------------------------------------------------------------------------
__global__ __launch_bounds__(256) void reduce_add(float4* __restrict__ out,
                                                  const float4* __restrict__ p) {
  const int i = blockIdx.x * 256 + threadIdx.x;
  float4 a = out[i], b = p[i];
  out[i] = float4{a.x + b.x, a.y + b.y, a.z + b.z, a.w + b.w};
}

// -------------------------------------------------------------------------
// stage 0 merged: blocks 0..4095 = E f32->bf16 cast (4 elems/thread);
// blocks 4096..7167 = the three W transposes (32x32 tiles).
// -------------------------------------------------------------------------
__global__ __launch_bounds__(256) void prep(
    const float* __restrict__ E,
    const float* __restrict__ w0, const float* __restrict__ w1,
    const float* __restrict__ w2,
    u16* __restrict__ Ebf, u16* __restrict__ Wt)
{
  int b = blockIdx.x;
  if (b < 4096) {
    const int i = (b * 256 + threadIdx.x) * 4;
    float4 f = *(const float4*)(E + i);
    u16x4 o;
    o.x = f2bf(f.x); o.y = f2bf(f.y); o.z = f2bf(f.z); o.w = f2bf(f.w);
    *(u16x4*)(Ebf + i) = o;
  } else {
    b -= 4096;
    const int which = b >> 10;           // 0..2
    const int tile = b & 1023;
    const float* in = (which == 0) ? w0 : (which == 1) ? w1 : w2;
    u16* o = Wt + (size_t)which * 1024 * 1024;
    const int c0 = (tile & 31) * 32, r0 = (tile >> 5) * 32;
    __shared__ u16 tl[32][33];
    const int tx = threadIdx.x & 31, ty0 = threadIdx.x >> 5;  // ty0: 0..7
#pragma unroll
    for (int k = 0; k < 4; ++k) {
      const int ty = ty0 + k * 8;
      tl[ty][tx] = f2bf(in[(size_t)(r0 + ty) * 1024 + c0 + tx]);
    }
    __syncthreads();
#pragma unroll
    for (int k = 0; k < 4; ++k) {
      const int ty = ty0 + k * 8;
      o[(size_t)(c0 + ty) * 1024 + r0 + tx] = tl[tx][ty];
    }
  }
}

// -------------------------------------------------------------------------
// stage 3: row softmax, in-place on bf16 S[4096][4096] (scale pre-applied).
// -------------------------------------------------------------------------
__global__ __launch_bounds__(256) void softmax_rows(u16* __restrict__ S) {
  const int N = 4096;
  u16* p = S + (size_t)blockIdx.x * N;
  const int t = threadIdx.x;
  u16x8 u0 = ((const u16x8*)p)[t * 2];
  u16x8 u1 = ((const u16x8*)p)[t * 2 + 1];
  float v[16];
#pragma unroll
  for (int i = 0; i < 8; ++i) v[i] = bf2f(u0[i]);
#pragma unroll
  for (int i = 0; i < 8; ++i) v[8 + i] = bf2f(u1[i]);

  float m = -1e30f;
#pragma unroll
  for (int i = 0; i < 16; ++i) m = fmaxf(m, v[i]);
#pragma unroll
  for (int off = 32; off; off >>= 1) m = fmaxf(m, __shfl_xor(m, off));
  __shared__ float red[8];
  if ((t & 63) == 0) red[t >> 6] = m;
  __syncthreads();
  m = fmaxf(fmaxf(red[0], red[1]), fmaxf(red[2], red[3]));

  float s = 0.f;
#pragma unroll
  for (int i = 0; i < 16; ++i) { v[i] = __expf(v[i] - m); s += v[i]; }
#pragma unroll
  for (int off = 32; off; off >>= 1) s += __shfl_xor(s, off);
  if ((t & 63) == 0) red[4 + (t >> 6)] = s;
  __syncthreads();
  s = (red[4] + red[5]) + (red[6] + red[7]);
  const float inv = 1.0f / s;

  u16x8 o0, o1;
#pragma unroll
  for (int i = 0; i < 8; ++i) o0[i] = f2bf(v[i] * inv);
#pragma unroll
  for (int i = 0; i < 8; ++i) o1[i] = f2bf(v[8 + i] * inv);
  ((u16x8*)p)[t * 2] = o0;
  ((u16x8*)p)[t * 2 + 1] = o1;
}

// -------------------------------------------------------------------------
// S=4096, D_IN=1024, D_OUT=1024.  fp32 in, fp32 out.
// ws layout (bytes): Ebf 8MB | Wt 6MB | QKV 24MB | Vt 8MB | S 32MB = 78MB
// PV partial (16MB fp32) reuses [0,16MB) -- dead once score completes.
// 6 dispatches: prep -> qkv -> score_tv -> softmax -> pv -> reduce.
// -------------------------------------------------------------------------
extern "C" void kernel_launch(void* const* d_in, const int* in_sizes, int n_in,
                              void* d_out, int out_size, void* d_ws, size_t ws_size,
                              hipStream_t stream) {
  const float* E  = (const float*)d_in[0];
  const float* Wq = (const float*)d_in[1];
  const float* Wk = (const float*)d_in[2];
  const float* Wv = (const float*)d_in[3];
  float* Out = (float*)d_out;

  char* w = (char*)d_ws;
  u16* Ebf = (u16*)(w);
  u16* Wt  = (u16*)(w + (size_t)(8u << 20));
  u16* QKV = (u16*)(w + (size_t)(14u << 20));
  u16* Vt  = (u16*)(w + (size_t)(38u << 20));
  u16* S   = (u16*)(w + (size_t)(46u << 20));
  float* P1 = (float*)(w);                 // PV split-K partial, dead region

  // stage 0: E cast + W transposes, one dispatch
  prep<<<7168, 256, 0, stream>>>(E, Wq, Wk, Wv, Ebf, Wt);

  // stage 1: QKV = E @ Wt^T   [4096 x 3072], K=1024
  gemm_qkv<<<768, 256, 0, stream>>>(Ebf, Wt, QKV);

  // stage 2: S = (Q @ K^T) / 32  +  V^T, one dispatch
  score_tv<<<5120, 256, 0, stream>>>(QKV, S, Vt);

  // stage 3: P = softmax(S) in place
  softmax_rows<<<4096, 256, 0, stream>>>(S);

  // stage 4: Out = P @ Vt^T, split-K=2 (z=0 -> Out, z=1 -> P1), then reduce
  gemm_pv<<<dim3(256, 1, 2), 256, 0, stream>>>(S, Vt, Out, P1);
  reduce_add<<<4096, 256, 0, stream>>>((float4*)Out, (const float4*)P1);
}

// Round 11
// 217.484 us; speedup vs baseline: 1.1097x; 1.0117x over previous
//
#include <hip/hip_runtime.h>
#include <hip/hip_bf16.h>

typedef unsigned short u16;
typedef __bf16 bf16x8 __attribute__((ext_vector_type(8)));
typedef float f32x4 __attribute__((ext_vector_type(4)));
typedef unsigned short u16x8 __attribute__((ext_vector_type(8)));
typedef unsigned short u16x4 __attribute__((ext_vector_type(4)));

__device__ __forceinline__ float bf2f(u16 u) {
  unsigned x = ((unsigned)u) << 16;
  return __builtin_bit_cast(float, x);
}
__device__ __forceinline__ u16 f2bf(float f) {
  unsigned u = __builtin_bit_cast(unsigned, f);
  u += 0x7fffu + ((u >> 16) & 1u);
  return (u16)(u >> 16);
}

// async global -> LDS, 16B per lane; lds base is wave-uniform,
// HW scatters at base + lane*16.
__device__ __forceinline__ void gload16(const u16* g, u16* lds) {
  __builtin_amdgcn_global_load_lds(
      (const __attribute__((address_space(1))) void*)g,
      (__attribute__((address_space(3))) void*)lds,
      16, 0, 0);
}

// -------------------------------------------------------------------------
// C[M,N] = A[M,K(range)] * B[N,K]^T, bf16 row-major, strides lda/ldb.
// 128xBN tile (BN in {64,128}), BK in {64,128}, 4 waves; each wave computes
// 64 x (BN/2) via 4 x (BN/32) MFMA 16x16x32 accumulators.
// LDS (caller-provided): [rows][BK] u16; 16B chunks XOR-swizzled
// (slot c ^ (row&7)) -> conflict-free banking with a contiguous
// global_load_lds lane scatter (global address permuted per lane).
// Block map: by = (bid&7) + 8*(bid/(8*NX)) -> A-panel sharers on one XCD.
// K-loop: plain 2-barrier structure.  Session facts: atomic split-K
// regresses (R2/R4); atomic-free split-K wins at 1 blk/CU (R9) but narrow
// BN=64 tiles buy the same occupancy without the partial+reduce traffic
// (R11); source-level vmcnt pipelining is compiler-defeated (R6 = m131);
// BK=128 halves the fixed per-iter drain stall at low occupancy (R7);
// SQ_LDS_BANK_CONFLICT==2^22 is a saturated counter artifact (R8).
// OUT_MODE: 0 = f32 store, 1 = bf16 store (scaled by cscale).
// -------------------------------------------------------------------------
template <int OUT_MODE, int NX, int BK, int BN>
__device__ __forceinline__ void gemm_body(
    const u16* __restrict__ A, int lda,
    const u16* __restrict__ B, int ldb,
    void* __restrict__ C, int ldc, int kt0, int Kc, float cscale,
    u16* As, u16* Bs, int bid)
{
  constexpr int CPR = BK / 8;      // 16B chunks per LDS row
  constexpr int RPG = 512 / BK;    // rows covered by one gload16
  constexpr int IPA = 32 / RPG;    // gload16 per wave for the 128-row A tile
  constexpr int IPB = (BN / 4) / RPG;  // gload16 per wave for the BN-row B tile
  constexpr int NWN = BN / 32;     // 16-wide n-subtiles per wave

  const int by = (bid & 7) + 8 * (bid / (8 * NX));
  const int bx = (bid >> 3) % NX;
  const int m0 = by * 128, n0 = bx * BN;

  const int t = threadIdx.x;
  const int w = t >> 6, l = t & 63;
  const int srow = l / CPR;                  // staging row within group
  const int lc = l % CPR;                    // staging chunk slot within row
  const int wm = (w >> 1) * 64;
  const int wn = (w & 1) * (BN / 2);
  const int fr = l & 15;                     // fragment row
  const int q = l >> 4;                      // quarter-wave 0..3

  f32x4 acc[4][NWN] = {};

  for (int kk = 0; kk < Kc; kk += BK) {
    const int kt = kt0 + kk;
    __syncthreads();
#pragma unroll
    for (int j = 0; j < IPA; ++j) {
      const int rr = RPG * (IPA * w + j);    // wave-uniform row-group base
      const int ga = rr + srow;
      const int sch = ((lc ^ (ga & 7))) * 8; // swizzled global chunk (elems)
      gload16(A + (size_t)(m0 + ga) * lda + kt + sch, As + rr * BK);
    }
#pragma unroll
    for (int j = 0; j < IPB; ++j) {
      const int rr = RPG * (IPB * w + j);
      const int gb = rr + srow;
      const int sch = ((lc ^ (gb & 7))) * 8;
      gload16(B + (size_t)(n0 + gb) * ldb + kt + sch, Bs + rr * BK);
    }
    __syncthreads();

#pragma unroll
    for (int s = 0; s < BK / 32; ++s) {      // K=32 MFMA steps per tile
      const int j = s * 4 + q;               // global 16B chunk index
      bf16x8 af[4], bfr[NWN];
#pragma unroll
      for (int i = 0; i < 4; ++i) {
        const int ra = wm + 16 * i + fr;
        af[i] = *(const bf16x8*)(As + ra * BK + (j ^ (ra & 7)) * 8);
      }
#pragma unroll
      for (int i = 0; i < NWN; ++i) {
        const int rb = wn + 16 * i + fr;
        bfr[i] = *(const bf16x8*)(Bs + rb * BK + (j ^ (rb & 7)) * 8);
      }
#pragma unroll
      for (int i = 0; i < 4; ++i)
#pragma unroll
        for (int jj = 0; jj < NWN; ++jj)
          acc[i][jj] = __builtin_amdgcn_mfma_f32_16x16x32_bf16(af[i], bfr[jj], acc[i][jj], 0, 0, 0);
    }
  }

  // C/D layout (m89-verified): col = lane&15, row = (lane>>4)*4 + reg
  const int er = q * 4;
  const int ec = l & 15;
#pragma unroll
  for (int i = 0; i < 4; ++i)
#pragma unroll
    for (int jj = 0; jj < NWN; ++jj)
#pragma unroll
      for (int r = 0; r < 4; ++r) {
        const size_t idx = (size_t)(m0 + wm + 16 * i + er + r) * ldc + (n0 + wn + 16 * jj + ec);
        if (OUT_MODE == 1) ((u16*)C)[idx] = f2bf(acc[i][jj][r] * cscale);
        else               ((float*)C)[idx] = acc[i][jj][r];
      }
}

// -------------------------------------------------------------------------
// stage 1: QKV = E @ Wt^T   [4096 x 3072], K=1024
// -------------------------------------------------------------------------
__global__ __launch_bounds__(256) void gemm_qkv(const u16* __restrict__ A,
                                                const u16* __restrict__ B,
                                                u16* __restrict__ C) {
  __shared__ __align__(16) u16 As[128 * 64], Bs[128 * 64];
  gemm_body<1, 24, 64, 128>(A, 1024, B, 1024, C, 3072, 0, 1024, 1.0f, As, Bs, blockIdx.x);
}

// -------------------------------------------------------------------------
// stage 2 merged: blocks 0..1023 = score GEMM S = (Q@K^T)/32;
// blocks 1024..5119 = V transpose (32x32 tiles).  tV tile aliases As so
// score keeps 32 KB LDS (5 blocks/CU).
// -------------------------------------------------------------------------
__global__ __launch_bounds__(256) void score_tv(const u16* __restrict__ QKV,
                                                u16* __restrict__ S,
                                                u16* __restrict__ Vt) {
  __shared__ __align__(16) u16 As[128 * 64], Bs[128 * 64];
  const int b = blockIdx.x;
  if (b < 1024) {
    gemm_body<1, 32, 64, 128>(QKV, 3072, QKV + 1024, 3072, S, 4096, 0, 1024,
                              0.03125f, As, Bs, b);
  } else {
    const int v = b - 1024;                       // 0..4095
    const int c0 = (v & 31) * 32;                 // V col 0..1023
    const int r0 = (v >> 5) * 32;                 // V row 0..4095
    u16 (*tl)[33] = (u16(*)[33])As;               // 2.1 KB alias of As
    const int tx = threadIdx.x & 31, ty0 = threadIdx.x >> 5;
    const u16* Vin = QKV + 2048;                  // V cols of QKV (ld 3072)
#pragma unroll
    for (int k = 0; k < 4; ++k) {
      const int ty = ty0 + k * 8;
      tl[ty][tx] = Vin[(size_t)(r0 + ty) * 3072 + c0 + tx];
    }
    __syncthreads();
#pragma unroll
    for (int k = 0; k < 4; ++k) {
      const int ty = ty0 + k * 8;
      Vt[(size_t)(c0 + ty) * 4096 + r0 + tx] = tl[tx][ty];
    }
  }
}

// -------------------------------------------------------------------------
// stage 4: Out = P @ Vt^T  [4096 x 1024], K=4096, BK=128, 128x64 tiles
// (grid 32x16 = 512 blocks, 48 KB LDS -> 3 blocks/CU).  No split-K, no
// partial, no reduce -- occupancy bought with tile shape instead (R11).
// -------------------------------------------------------------------------
__global__ __launch_bounds__(256) void gemm_pv(const u16* __restrict__ S,
                                               const u16* __restrict__ Vt,
                                               float* __restrict__ O) {
  __shared__ __align__(16) u16 As[128 * 128], Bs[64 * 128];
  gemm_body<0, 16, 128, 64>(S, 4096, Vt, 4096, O, 1024, 0, 4096,
                            1.0f, As, Bs, blockIdx.x);
}

// -------------------------------------------------------------------------
// stage 0 merged: blocks 0..4095 = E f32->bf16 cast (4 elems/thread);
// blocks 4096..7167 = the three W transposes (32x32 tiles).
// -------------------------------------------------------------------------
__global__ __launch_bounds__(256) void prep(
    const float* __restrict__ E,
    const float* __restrict__ w0, const float* __restrict__ w1,
    const float* __restrict__ w2,
    u16* __restrict__ Ebf, u16* __restrict__ Wt)
{
  int b = blockIdx.x;
  if (b < 4096) {
    const int i = (b * 256 + threadIdx.x) * 4;
    float4 f = *(const float4*)(E + i);
    u16x4 o;
    o.x = f2bf(f.x); o.y = f2bf(f.y); o.z = f2bf(f.z); o.w = f2bf(f.w);
    *(u16x4*)(Ebf + i) = o;
  } else {
    b -= 4096;
    const int which = b >> 10;           // 0..2
    const int tile = b & 1023;
    const float* in = (which == 0) ? w0 : (which == 1) ? w1 : w2;
    u16* o = Wt + (size_t)which * 1024 * 1024;
    const int c0 = (tile & 31) * 32, r0 = (tile >> 5) * 32;
    __shared__ u16 tl[32][33];
    const int tx = threadIdx.x & 31, ty0 = threadIdx.x >> 5;  // ty0: 0..7
#pragma unroll
    for (int k = 0; k < 4; ++k) {
      const int ty = ty0 + k * 8;
      tl[ty][tx] = f2bf(in[(size_t)(r0 + ty) * 1024 + c0 + tx]);
    }
    __syncthreads();
#pragma unroll
    for (int k = 0; k < 4; ++k) {
      const int ty = ty0 + k * 8;
      o[(size_t)(c0 + ty) * 1024 + r0 + tx] = tl[tx][ty];
    }
  }
}

// -------------------------------------------------------------------------
// stage 3: row softmax, in-place on bf16 S[4096][4096] (scale pre-applied).
// -------------------------------------------------------------------------
__global__ __launch_bounds__(256) void softmax_rows(u16* __restrict__ S) {
  const int N = 4096;
  u16* p = S + (size_t)blockIdx.x * N;
  const int t = threadIdx.x;
  u16x8 u0 = ((const u16x8*)p)[t * 2];
  u16x8 u1 = ((const u16x8*)p)[t * 2 + 1];
  float v[16];
#pragma unroll
  for (int i = 0; i < 8; ++i) v[i] = bf2f(u0[i]);
#pragma unroll
  for (int i = 0; i < 8; ++i) v[8 + i] = bf2f(u1[i]);

  float m = -1e30f;
#pragma unroll
  for (int i = 0; i < 16; ++i) m = fmaxf(m, v[i]);
#pragma unroll
  for (int off = 32; off; off >>= 1) m = fmaxf(m, __shfl_xor(m, off));
  __shared__ float red[8];
  if ((t & 63) == 0) red[t >> 6] = m;
  __syncthreads();
  m = fmaxf(fmaxf(red[0], red[1]), fmaxf(red[2], red[3]));

  float s = 0.f;
#pragma unroll
  for (int i = 0; i < 16; ++i) { v[i] = __expf(v[i] - m); s += v[i]; }
#pragma unroll
  for (int off = 32; off; off >>= 1) s += __shfl_xor(s, off);
  if ((t & 63) == 0) red[4 + (t >> 6)] = s;
  __syncthreads();
  s = (red[4] + red[5]) + (red[6] + red[7]);
  const float inv = 1.0f / s;

  u16x8 o0, o1;
#pragma unroll
  for (int i = 0; i < 8; ++i) o0[i] = f2bf(v[i] * inv);
#pragma unroll
  for (int i = 0; i < 8; ++i) o1[i] = f2bf(v[8 + i] * inv);
  ((u16x8*)p)[t * 2] = o0;
  ((u16x8*)p)[t * 2 + 1] = o1;
}

// -------------------------------------------------------------------------
// S=4096, D_IN=1024, D_OUT=1024.  fp32 in, fp32 out.
// ws layout (bytes): Ebf 8MB | Wt 6MB | QKV 24MB | Vt 8MB | S 32MB = 78MB
// 5 dispatches: prep -> qkv -> score_tv -> softmax -> pv.
// -------------------------------------------------------------------------
extern "C" void kernel_launch(void* const* d_in, const int* in_sizes, int n_in,
                              void* d_out, int out_size, void* d_ws, size_t ws_size,
                              hipStream_t stream) {
  const float* E  = (const float*)d_in[0];
  const float* Wq = (const float*)d_in[1];
  const float* Wk = (const float*)d_in[2];
  const float* Wv = (const float*)d_in[3];
  float* Out = (float*)d_out;

  char* w = (char*)d_ws;
  u16* Ebf = (u16*)(w);
  u16* Wt  = (u16*)(w + (size_t)(8u << 20));
  u16* QKV = (u16*)(w + (size_t)(14u << 20));
  u16* Vt  = (u16*)(w + (size_t)(38u << 20));
  u16* S   = (u16*)(w + (size_t)(46u << 20));

  // stage 0: E cast + W transposes, one dispatch
  prep<<<7168, 256, 0, stream>>>(E, Wq, Wk, Wv, Ebf, Wt);

  // stage 1: QKV = E @ Wt^T   [4096 x 3072], K=1024
  gemm_qkv<<<768, 256, 0, stream>>>(Ebf, Wt, QKV);

  // stage 2: S = (Q @ K^T) / 32  +  V^T, one dispatch
  score_tv<<<5120, 256, 0, stream>>>(QKV, S, Vt);

  // stage 3: P = softmax(S) in place
  softmax_rows<<<4096, 256, 0, stream>>>(S);

  // stage 4: Out = P @ Vt^T, 128x64 tiles, no split-K
  gemm_pv<<<512, 256, 0, stream>>>(S, Vt, Out);
}

// Round 12
// 217.055 us; speedup vs baseline: 1.1119x; 1.0020x over previous
//
#include <hip/hip_runtime.h>
#include <hip/hip_bf16.h>

typedef unsigned short u16;
typedef __bf16 bf16x8 __attribute__((ext_vector_type(8)));
typedef float f32x4 __attribute__((ext_vector_type(4)));
typedef unsigned short u16x8 __attribute__((ext_vector_type(8)));
typedef unsigned short u16x4 __attribute__((ext_vector_type(4)));

__device__ __forceinline__ float bf2f(u16 u) {
  unsigned x = ((unsigned)u) << 16;
  return __builtin_bit_cast(float, x);
}
__device__ __forceinline__ u16 f2bf(float f) {
  unsigned u = __builtin_bit_cast(unsigned, f);
  u += 0x7fffu + ((u >> 16) & 1u);
  return (u16)(u >> 16);
}

// async global -> LDS, 16B per lane; lds base is wave-uniform,
// HW scatters at base + lane*16.
__device__ __forceinline__ void gload16(const u16* g, u16* lds) {
  __builtin_amdgcn_global_load_lds(
      (const __attribute__((address_space(1))) void*)g,
      (__attribute__((address_space(3))) void*)lds,
      16, 0, 0);
}

// -------------------------------------------------------------------------
// C[M,N] = A[M,K(range)] * B[N,K]^T, bf16 row-major, strides lda/ldb.
// 128xBN tile (BN in {64,128}), BK in {64,128}, 4 waves; each wave computes
// 64 x (BN/2) via 4 x (BN/32) MFMA 16x16x32 accumulators.
// LDS (caller-provided single arena): As = lds (128*BK), Bs follows;
// 16B chunks XOR-swizzled (slot c ^ (row&7)) -> conflict-free banking with
// a contiguous global_load_lds lane scatter (global address permuted).
// Block map: by = (bid&7) + 8*(bid/(8*NX)) -> A-panel sharers on one XCD.
// K-loop: plain 2-barrier structure.  Session facts: atomic split-K
// regresses (R2/R4); narrow BN=64 tiles buy PV occupancy without
// partial+reduce traffic (R11); source-level vmcnt pipelining is
// compiler-defeated (R6 = m131); BK=128 halves the fixed per-iter drain
// stall at low occupancy (R7); SQ_LDS_BANK_CONFLICT==2^22 is a saturated
// counter artifact (R8).
// Epilogue (R12): C round-trips through the wave's private LDS region
// (aliasing As/Bs, row stride 72 u16 / 40 f32 -> 16B-aligned b128 reads,
// bank rotation conflict-free), then 8 coalesced 16B stores per wave
// instead of 64 scalar column-strided stores.
// OUT_MODE: 0 = f32 store, 1 = bf16 store (scaled by cscale).
// -------------------------------------------------------------------------
template <int OUT_MODE, int NX, int BK, int BN>
__device__ __forceinline__ void gemm_body(
    const u16* __restrict__ A, int lda,
    const u16* __restrict__ B, int ldb,
    void* __restrict__ C, int ldc, int kt0, int Kc, float cscale,
    u16* lds, int bid)
{
  u16* As = lds;
  u16* Bs = lds + 128 * BK;

  constexpr int CPR = BK / 8;      // 16B chunks per LDS row
  constexpr int RPG = 512 / BK;    // rows covered by one gload16
  constexpr int IPA = 32 / RPG;    // gload16 per wave for the 128-row A tile
  constexpr int IPB = (BN / 4) / RPG;  // gload16 per wave for the BN-row B tile
  constexpr int NWN = BN / 32;     // 16-wide n-subtiles per wave

  const int by = (bid & 7) + 8 * (bid / (8 * NX));
  const int bx = (bid >> 3) % NX;
  const int m0 = by * 128, n0 = bx * BN;

  const int t = threadIdx.x;
  const int w = t >> 6, l = t & 63;
  const int srow = l / CPR;                  // staging row within group
  const int lc = l % CPR;                    // staging chunk slot within row
  const int wm = (w >> 1) * 64;
  const int wn = (w & 1) * (BN / 2);
  const int fr = l & 15;                     // fragment row
  const int q = l >> 4;                      // quarter-wave 0..3

  f32x4 acc[4][NWN] = {};

  for (int kk = 0; kk < Kc; kk += BK) {
    const int kt = kt0 + kk;
    __syncthreads();
#pragma unroll
    for (int j = 0; j < IPA; ++j) {
      const int rr = RPG * (IPA * w + j);    // wave-uniform row-group base
      const int ga = rr + srow;
      const int sch = ((lc ^ (ga & 7))) * 8; // swizzled global chunk (elems)
      gload16(A + (size_t)(m0 + ga) * lda + kt + sch, As + rr * BK);
    }
#pragma unroll
    for (int j = 0; j < IPB; ++j) {
      const int rr = RPG * (IPB * w + j);
      const int gb = rr + srow;
      const int sch = ((lc ^ (gb & 7))) * 8;
      gload16(B + (size_t)(n0 + gb) * ldb + kt + sch, Bs + rr * BK);
    }
    __syncthreads();

#pragma unroll
    for (int s = 0; s < BK / 32; ++s) {      // K=32 MFMA steps per tile
      const int j = s * 4 + q;               // global 16B chunk index
      bf16x8 af[4], bfr[NWN];
#pragma unroll
      for (int i = 0; i < 4; ++i) {
        const int ra = wm + 16 * i + fr;
        af[i] = *(const bf16x8*)(As + ra * BK + (j ^ (ra & 7)) * 8);
      }
#pragma unroll
      for (int i = 0; i < NWN; ++i) {
        const int rb = wn + 16 * i + fr;
        bfr[i] = *(const bf16x8*)(Bs + rb * BK + (j ^ (rb & 7)) * 8);
      }
#pragma unroll
      for (int i = 0; i < 4; ++i)
#pragma unroll
        for (int jj = 0; jj < NWN; ++jj)
          acc[i][jj] = __builtin_amdgcn_mfma_f32_16x16x32_bf16(af[i], bfr[jj], acc[i][jj], 0, 0, 0);
    }
  }

  // ---- epilogue: LDS round-trip, then coalesced 16B stores ----
  // C/D layout (m89-verified): col = lane&15, row = (lane>>4)*4 + reg
  __syncthreads();                           // As/Bs now free for reuse
  const int er = q * 4;
  const int ec = l & 15;
  const int g = l >> 3, c = l & 7;

  if (OUT_MODE == 1) {
    u16* eb = lds + w * 4608;                // 64 rows x 72 u16 (9216 B)
#pragma unroll
    for (int i = 0; i < 4; ++i)
#pragma unroll
      for (int jj = 0; jj < NWN; ++jj)
#pragma unroll
        for (int r = 0; r < 4; ++r)
          eb[(16 * i + er + r) * 72 + 16 * jj + ec] = f2bf(acc[i][jj][r] * cscale);
#pragma unroll
    for (int k = 0; k < 8; ++k) {
      const int row = k * 8 + g;
      u16x8 v = *(const u16x8*)(eb + row * 72 + c * 8);
      *(u16x8*)((u16*)C + (size_t)(m0 + wm + row) * ldc + n0 + wn + c * 8) = v;
    }
  } else {
    float* eb = (float*)lds + w * 2560;      // 64 rows x 40 f32 (10240 B)
#pragma unroll
    for (int i = 0; i < 4; ++i)
#pragma unroll
      for (int jj = 0; jj < NWN; ++jj)
#pragma unroll
        for (int r = 0; r < 4; ++r)
          eb[(16 * i + er + r) * 40 + 16 * jj + ec] = acc[i][jj][r];
#pragma unroll
    for (int k = 0; k < 8; ++k) {
      const int row = k * 8 + g;
      float4 v = *(const float4*)(eb + row * 40 + c * 4);
      *(float4*)((float*)C + (size_t)(m0 + wm + row) * ldc + n0 + wn + c * 4) = v;
    }
  }
}

// -------------------------------------------------------------------------
// stage 1: QKV = E @ Wt^T   [4096 x 3072], K=1024
// LDS: max(K-loop 32 KB, epilogue 4x9216=36 KB) = 36 KB -> 4 blocks/CU cap
// (grid gives 3/CU anyway).
// -------------------------------------------------------------------------
__global__ __launch_bounds__(256) void gemm_qkv(const u16* __restrict__ A,
                                                const u16* __restrict__ B,
                                                u16* __restrict__ C) {
  __shared__ __align__(16) u16 lds[18432];   // 36864 B
  gemm_body<1, 24, 64, 128>(A, 1024, B, 1024, C, 3072, 0, 1024, 1.0f, lds, blockIdx.x);
}

// -------------------------------------------------------------------------
// stage 2 merged: blocks 0..1023 = score GEMM S = (Q@K^T)/32;
// blocks 1024..5119 = V transpose (32x32 tiles).  tV tile aliases lds.
// -------------------------------------------------------------------------
__global__ __launch_bounds__(256) void score_tv(const u16* __restrict__ QKV,
                                                u16* __restrict__ S,
                                                u16* __restrict__ Vt) {
  __shared__ __align__(16) u16 lds[18432];   // 36864 B
  const int b = blockIdx.x;
  if (b < 1024) {
    gemm_body<1, 32, 64, 128>(QKV, 3072, QKV + 1024, 3072, S, 4096, 0, 1024,
                              0.03125f, lds, b);
  } else {
    const int v = b - 1024;                       // 0..4095
    const int c0 = (v & 31) * 32;                 // V col 0..1023
    const int r0 = (v >> 5) * 32;                 // V row 0..4095
    u16 (*tl)[33] = (u16(*)[33])lds;              // 2.1 KB alias
    const int tx = threadIdx.x & 31, ty0 = threadIdx.x >> 5;
    const u16* Vin = QKV + 2048;                  // V cols of QKV (ld 3072)
#pragma unroll
    for (int k = 0; k < 4; ++k) {
      const int ty = ty0 + k * 8;
      tl[ty][tx] = Vin[(size_t)(r0 + ty) * 3072 + c0 + tx];
    }
    __syncthreads();
#pragma unroll
    for (int k = 0; k < 4; ++k) {
      const int ty = ty0 + k * 8;
      Vt[(size_t)(c0 + ty) * 4096 + r0 + tx] = tl[tx][ty];
    }
  }
}

// -------------------------------------------------------------------------
// stage 4: Out = P @ Vt^T  [4096 x 1024], K=4096, BK=128, 128x64 tiles
// (grid 32x16 = 512 blocks, 48 KB LDS -> 3 blocks/CU).  No split-K (R11).
// -------------------------------------------------------------------------
__global__ __launch_bounds__(256) void gemm_pv(const u16* __restrict__ S,
                                               const u16* __restrict__ Vt,
                                               float* __restrict__ O) {
  __shared__ __align__(16) u16 lds[24576];   // 49152 B
  gemm_body<0, 16, 128, 64>(S, 4096, Vt, 4096, O, 1024, 0, 4096,
                            1.0f, lds, blockIdx.x);
}

// -------------------------------------------------------------------------
// stage 0 merged: blocks 0..4095 = E f32->bf16 cast (4 elems/thread);
// blocks 4096..7167 = the three W transposes (32x32 tiles).
// -------------------------------------------------------------------------
__global__ __launch_bounds__(256) void prep(
    const float* __restrict__ E,
    const float* __restrict__ w0, const float* __restrict__ w1,
    const float* __restrict__ w2,
    u16* __restrict__ Ebf, u16* __restrict__ Wt)
{
  int b = blockIdx.x;
  if (b < 4096) {
    const int i = (b * 256 + threadIdx.x) * 4;
    float4 f = *(const float4*)(E + i);
    u16x4 o;
    o.x = f2bf(f.x); o.y = f2bf(f.y); o.z = f2bf(f.z); o.w = f2bf(f.w);
    *(u16x4*)(Ebf + i) = o;
  } else {
    b -= 4096;
    const int which = b >> 10;           // 0..2
    const int tile = b & 1023;
    const float* in = (which == 0) ? w0 : (which == 1) ? w1 : w2;
    u16* o = Wt + (size_t)which * 1024 * 1024;
    const int c0 = (tile & 31) * 32, r0 = (tile >> 5) * 32;
    __shared__ u16 tl[32][33];
    const int tx = threadIdx.x & 31, ty0 = threadIdx.x >> 5;  // ty0: 0..7
#pragma unroll
    for (int k = 0; k < 4; ++k) {
      const int ty = ty0 + k * 8;
      tl[ty][tx] = f2bf(in[(size_t)(r0 + ty) * 1024 + c0 + tx]);
    }
    __syncthreads();
#pragma unroll
    for (int k = 0; k < 4; ++k) {
      const int ty = ty0 + k * 8;
      o[(size_t)(c0 + ty) * 1024 + r0 + tx] = tl[tx][ty];
    }
  }
}

// -------------------------------------------------------------------------
// stage 3: row softmax, in-place on bf16 S[4096][4096] (scale pre-applied).
// -------------------------------------------------------------------------
__global__ __launch_bounds__(256) void softmax_rows(u16* __restrict__ S) {
  const int N = 4096;
  u16* p = S + (size_t)blockIdx.x * N;
  const int t = threadIdx.x;
  u16x8 u0 = ((const u16x8*)p)[t * 2];
  u16x8 u1 = ((const u16x8*)p)[t * 2 + 1];
  float v[16];
#pragma unroll
  for (int i = 0; i < 8; ++i) v[i] = bf2f(u0[i]);
#pragma unroll
  for (int i = 0; i < 8; ++i) v[8 + i] = bf2f(u1[i]);

  float m = -1e30f;
#pragma unroll
  for (int i = 0; i < 16; ++i) m = fmaxf(m, v[i]);
#pragma unroll
  for (int off = 32; off; off >>= 1) m = fmaxf(m, __shfl_xor(m, off));
  __shared__ float red[8];
  if ((t & 63) == 0) red[t >> 6] = m;
  __syncthreads();
  m = fmaxf(fmaxf(red[0], red[1]), fmaxf(red[2], red[3]));

  float s = 0.f;
#pragma unroll
  for (int i = 0; i < 16; ++i) { v[i] = __expf(v[i] - m); s += v[i]; }
#pragma unroll
  for (int off = 32; off; off >>= 1) s += __shfl_xor(s, off);
  if ((t & 63) == 0) red[4 + (t >> 6)] = s;
  __syncthreads();
  s = (red[4] + red[5]) + (red[6] + red[7]);
  const float inv = 1.0f / s;

  u16x8 o0, o1;
#pragma unroll
  for (int i = 0; i < 8; ++i) o0[i] = f2bf(v[i] * inv);
#pragma unroll
  for (int i = 0; i < 8; ++i) o1[i] = f2bf(v[8 + i] * inv);
  ((u16x8*)p)[t * 2] = o0;
  ((u16x8*)p)[t * 2 + 1] = o1;
}

// -------------------------------------------------------------------------
// S=4096, D_IN=1024, D_OUT=1024.  fp32 in, fp32 out.
// ws layout (bytes): Ebf 8MB | Wt 6MB | QKV 24MB | Vt 8MB | S 32MB = 78MB
// 5 dispatches: prep -> qkv -> score_tv -> softmax -> pv.
// -------------------------------------------------------------------------
extern "C" void kernel_launch(void* const* d_in, const int* in_sizes, int n_in,
                              void* d_out, int out_size, void* d_ws, size_t ws_size,
                              hipStream_t stream) {
  const float* E  = (const float*)d_in[0];
  const float* Wq = (const float*)d_in[1];
  const float* Wk = (const float*)d_in[2];
  const float* Wv = (const float*)d_in[3];
  float* Out = (float*)d_out;

  char* w = (char*)d_ws;
  u16* Ebf = (u16*)(w);
  u16* Wt  = (u16*)(w + (size_t)(8u << 20));
  u16* QKV = (u16*)(w + (size_t)(14u << 20));
  u16* Vt  = (u16*)(w + (size_t)(38u << 20));
  u16* S   = (u16*)(w + (size_t)(46u << 20));

  // stage 0: E cast + W transposes, one dispatch
  prep<<<7168, 256, 0, stream>>>(E, Wq, Wk, Wv, Ebf, Wt);

  // stage 1: QKV = E @ Wt^T   [4096 x 3072], K=1024
  gemm_qkv<<<768, 256, 0, stream>>>(Ebf, Wt, QKV);

  // stage 2: S = (Q @ K^T) / 32  +  V^T, one dispatch
  score_tv<<<5120, 256, 0, stream>>>(QKV, S, Vt);

  // stage 3: P = softmax(S) in place
  softmax_rows<<<4096, 256, 0, stream>>>(S);

  // stage 4: Out = P @ Vt^T, 128x64 tiles, no split-K
  gemm_pv<<<512, 256, 0, stream>>>(S, Vt, Out);
}